// Round 1
// baseline (174.785 us; speedup 1.0000x reference)
//
#include <hip/hip_runtime.h>
#include <hip/hip_bf16.h>
#include <stdint.h>

// Problem constants: B=16, C=256, H=W=32 -> S=1024, NH=4, DK=64, N_qkv=768
typedef float f32x4 __attribute__((ext_vector_type(4)));
typedef __bf16 bf16x8 __attribute__((ext_vector_type(8)));
typedef unsigned short u16x8 __attribute__((ext_vector_type(8)));

#define MFMA16(a, b, c) __builtin_amdgcn_mfma_f32_16x16x32_bf16(a, b, c, 0, 0, 0)

static __device__ __forceinline__ unsigned short f2bf(float f) {
    uint32_t u = __builtin_bit_cast(uint32_t, f);
    u = u + 0x7FFFu + ((u >> 16) & 1u);
    return (unsigned short)(u >> 16);
}

static __device__ __forceinline__ bf16x8 ldb8(const unsigned short* p) {
    return __builtin_bit_cast(bf16x8, *reinterpret_cast<const u16x8*>(p));
}

// ---------------- kernel 1: weight convert+transpose -> bf16 [n][k] ----------------
__global__ __launch_bounds__(256) void k_weights(const float* __restrict__ wp,
                                                 const float* __restrict__ wo,
                                                 unsigned short* __restrict__ wpT,
                                                 unsigned short* __restrict__ woT) {
    int idx = blockIdx.x * 256 + threadIdx.x;
    for (int i = idx; i < 256 * 768; i += 256 * 256) {
        int k = i / 768, n = i - k * 768;
        wpT[n * 256 + k] = f2bf(wp[i]);       // coalesced read, scattered 2B write (small)
    }
    for (int i = idx; i < 256 * 256; i += 256 * 256) {
        int k = i >> 8, n = i & 255;
        woT[n * 256 + k] = f2bf(wo[i]);
    }
}

// ---------------- kernel 2: x [b][c][s] fp32 -> xT [b][s][c] bf16 ----------------
__global__ __launch_bounds__(256) void k_transpose_x(const float* __restrict__ x,
                                                     unsigned short* __restrict__ xT) {
    int bid = blockIdx.x;            // 16 b * 4 ct * 16 it = 1024
    int b  = bid >> 6;
    int ct = (bid >> 4) & 3;
    int it = bid & 15;
    int t = threadIdx.x;
    __shared__ __align__(16) unsigned short tile[64][72];

    int c  = t >> 2;                 // 0..63
    int ic = (t & 3) << 4;           // 0,16,32,48
    const float* xp = x + (((size_t)(b * 256 + ct * 64 + c)) << 10) + (it << 6) + ic;
#pragma unroll
    for (int j = 0; j < 4; ++j) {
        float4 v = reinterpret_cast<const float4*>(xp)[j];
        ushort4 hv;
        hv.x = f2bf(v.x); hv.y = f2bf(v.y); hv.z = f2bf(v.z); hv.w = f2bf(v.w);
        *reinterpret_cast<ushort4*>(&tile[c][ic + 4 * j]) = hv;
    }
    __syncthreads();
    int i  = t >> 2;                 // 0..63
    int cc = (t & 3) << 4;
    u16x8 o0, o1;
#pragma unroll
    for (int k = 0; k < 8; ++k) o0[k] = tile[cc + k][i];
#pragma unroll
    for (int k = 0; k < 8; ++k) o1[k] = tile[cc + 8 + k][i];
    unsigned short* dst = xT + (((size_t)(b * 1024 + it * 64 + i)) << 8) + ct * 64 + cc;
    *reinterpret_cast<u16x8*>(dst) = o0;
    *reinterpret_cast<u16x8*>(dst + 8) = o1;
}

// ---------------- kernel 3: QKV GEMM: qkv[m][768] = xT[m][256] @ wpT^T + bias ----------------
__global__ __launch_bounds__(256) void k_gemm_qkv(const unsigned short* __restrict__ xT,
                                                  const unsigned short* __restrict__ wT,
                                                  const float* __restrict__ bias,
                                                  unsigned short* __restrict__ qkv) {
    int bid = blockIdx.x;            // 128 mtiles * 6 ntiles
    int mt = bid / 6, nt = bid - mt * 6;
    int tid = threadIdx.x;
    int w = tid >> 6, l = tid & 63;
    int l15 = l & 15, lg = l >> 4;
    int wm = (w >> 1) * 64, wn = (w & 1) * 64;

    __shared__ __align__(16) unsigned short Al[128 * 40];
    __shared__ __align__(16) unsigned short Bl[128 * 40];

    f32x4 acc[4][4] = {};

    int sr = tid >> 1;               // 0..127
    int sc = (tid & 1) << 4;         // 0 or 16
    const unsigned short* Ag = xT + (((size_t)(mt * 128 + sr)) << 8) + sc;
    const unsigned short* Bg = wT + (((size_t)(nt * 128 + sr)) << 8) + sc;

    for (int kt = 0; kt < 256; kt += 32) {
        __syncthreads();
        {
            u16x8 a0 = *reinterpret_cast<const u16x8*>(Ag + kt);
            u16x8 a1 = *reinterpret_cast<const u16x8*>(Ag + kt + 8);
            u16x8 b0 = *reinterpret_cast<const u16x8*>(Bg + kt);
            u16x8 b1 = *reinterpret_cast<const u16x8*>(Bg + kt + 8);
            *reinterpret_cast<u16x8*>(&Al[sr * 40 + sc]) = a0;
            *reinterpret_cast<u16x8*>(&Al[sr * 40 + sc + 8]) = a1;
            *reinterpret_cast<u16x8*>(&Bl[sr * 40 + sc]) = b0;
            *reinterpret_cast<u16x8*>(&Bl[sr * 40 + sc + 8]) = b1;
        }
        __syncthreads();
        bf16x8 af[4], bfr[4];
#pragma unroll
        for (int mi = 0; mi < 4; ++mi)
            af[mi] = ldb8(&Al[(wm + mi * 16 + l15) * 40 + lg * 8]);
#pragma unroll
        for (int ni = 0; ni < 4; ++ni)
            bfr[ni] = ldb8(&Bl[(wn + ni * 16 + l15) * 40 + lg * 8]);
#pragma unroll
        for (int mi = 0; mi < 4; ++mi)
#pragma unroll
            for (int ni = 0; ni < 4; ++ni)
                acc[mi][ni] = MFMA16(af[mi], bfr[ni], acc[mi][ni]);
    }

#pragma unroll
    for (int ni = 0; ni < 4; ++ni) {
        int n = nt * 128 + wn + ni * 16 + l15;
        float bz = bias[n];
#pragma unroll
        for (int mi = 0; mi < 4; ++mi) {
            int mg = mt * 128 + wm + mi * 16 + lg * 4;
            unsigned short* qp = qkv + (size_t)mg * 768 + n;
#pragma unroll
            for (int r = 0; r < 4; ++r)
                qp[(size_t)r * 768] = f2bf(acc[mi][ni][r] + bz);
        }
    }
}

// ---------------- kernel 4: flash attention ----------------
// qkv layout: [b][s][h*192 + {q:0..63, k:64..127, v:128..191}] bf16
// out: ao [b][s][h*64+d] bf16
__global__ __launch_bounds__(256) void k_attn(const unsigned short* __restrict__ qkv,
                                              unsigned short* __restrict__ ao) {
    int bid = blockIdx.x;            // b(16) * h(4) * qt(8) = 512
    int qt = bid & 7;
    int h  = (bid >> 3) & 3;
    int b  = bid >> 5;
    int tid = threadIdx.x;
    int w = tid >> 6, l = tid & 63;
    int l15 = l & 15, lg = l >> 4;

    __shared__ __align__(16) unsigned short Kl[64][72];
    __shared__ __align__(16) unsigned short Vt[64][72];
    __shared__ __align__(16) unsigned short Pl[4][32][72];

    const size_t bb = (size_t)b * 1024;
    const unsigned short* qbase = qkv + bb * 768 + h * 192;

    bf16x8 qf[2][2];
#pragma unroll
    for (int mi = 0; mi < 2; ++mi)
#pragma unroll
        for (int kf = 0; kf < 2; ++kf) {
            int i = qt * 128 + w * 32 + mi * 16 + l15;
            qf[mi][kf] = ldb8(qbase + (size_t)i * 768 + kf * 32 + lg * 8);
        }

    f32x4 mrow[2], lrow[2], oacc[2][4];
#pragma unroll
    for (int mi = 0; mi < 2; ++mi)
#pragma unroll
        for (int r = 0; r < 4; ++r) { mrow[mi][r] = -1e30f; lrow[mi][r] = 0.0f; }
#pragma unroll
    for (int mi = 0; mi < 2; ++mi)
#pragma unroll
        for (int df = 0; df < 4; ++df)
#pragma unroll
            for (int r = 0; r < 4; ++r) oacc[mi][df][r] = 0.0f;

    int jj = tid >> 2;               // 0..63
    int dc = (tid & 3) << 4;         // 0,16,32,48
    const unsigned short* kg = qkv + bb * 768 + h * 192 + 64  + (size_t)jj * 768 + dc;
    const unsigned short* vg = qkv + bb * 768 + h * 192 + 128 + (size_t)jj * 768 + dc;

    for (int jt = 0; jt < 1024; jt += 64) {
        __syncthreads();
        {
            const unsigned short* kp = kg + (size_t)jt * 768;
            u16x8 k0 = *reinterpret_cast<const u16x8*>(kp);
            u16x8 k1 = *reinterpret_cast<const u16x8*>(kp + 8);
            *reinterpret_cast<u16x8*>(&Kl[jj][dc]) = k0;
            *reinterpret_cast<u16x8*>(&Kl[jj][dc + 8]) = k1;
            const unsigned short* vp = vg + (size_t)jt * 768;
            u16x8 v0 = *reinterpret_cast<const u16x8*>(vp);
            u16x8 v1 = *reinterpret_cast<const u16x8*>(vp + 8);
#pragma unroll
            for (int z = 0; z < 8; ++z) Vt[dc + z][jj] = v0[z];
#pragma unroll
            for (int z = 0; z < 8; ++z) Vt[dc + 8 + z][jj] = v1[z];
        }
        __syncthreads();

        // S = Q K^T
        f32x4 sa[2][4] = {};
#pragma unroll
        for (int ni = 0; ni < 4; ++ni) {
            bf16x8 kb0 = ldb8(&Kl[ni * 16 + l15][lg * 8]);
            bf16x8 kb1 = ldb8(&Kl[ni * 16 + l15][32 + lg * 8]);
#pragma unroll
            for (int mi = 0; mi < 2; ++mi) {
                sa[mi][ni] = MFMA16(qf[mi][0], kb0, sa[mi][ni]);
                sa[mi][ni] = MFMA16(qf[mi][1], kb1, sa[mi][ni]);
            }
        }

        // online softmax (rows = lg*4+r within each 16-block; cols spread over l15)
        f32x4 pm[2], ef[2], rs[2];
#pragma unroll
        for (int mi = 0; mi < 2; ++mi) {
#pragma unroll
            for (int ni = 0; ni < 4; ++ni)
#pragma unroll
                for (int r = 0; r < 4; ++r) sa[mi][ni][r] *= 0.125f;
            f32x4 p;
#pragma unroll
            for (int r = 0; r < 4; ++r)
                p[r] = fmaxf(fmaxf(sa[mi][0][r], sa[mi][1][r]), fmaxf(sa[mi][2][r], sa[mi][3][r]));
#pragma unroll
            for (int d = 1; d < 16; d <<= 1)
#pragma unroll
                for (int r = 0; r < 4; ++r) p[r] = fmaxf(p[r], __shfl_xor(p[r], d));
            pm[mi] = p;
        }
#pragma unroll
        for (int mi = 0; mi < 2; ++mi) {
#pragma unroll
            for (int r = 0; r < 4; ++r) {
                float mn = fmaxf(mrow[mi][r], pm[mi][r]);
                ef[mi][r] = __expf(mrow[mi][r] - mn);
                mrow[mi][r] = mn;
                rs[mi][r] = 0.0f;
            }
        }
#pragma unroll
        for (int mi = 0; mi < 2; ++mi)
#pragma unroll
            for (int ni = 0; ni < 4; ++ni)
#pragma unroll
                for (int r = 0; r < 4; ++r) {
                    float pv = __expf(sa[mi][ni][r] - mrow[mi][r]);
                    sa[mi][ni][r] = pv;
                    rs[mi][r] += pv;
                }
        // write P to per-wave LDS (bf16)
#pragma unroll
        for (int mi = 0; mi < 2; ++mi)
#pragma unroll
            for (int ni = 0; ni < 4; ++ni)
#pragma unroll
                for (int r = 0; r < 4; ++r)
                    Pl[w][mi * 16 + lg * 4 + r][ni * 16 + l15] = f2bf(sa[mi][ni][r]);
        // finish row-sum reduce + state update + O rescale
#pragma unroll
        for (int mi = 0; mi < 2; ++mi) {
#pragma unroll
            for (int d = 1; d < 16; d <<= 1)
#pragma unroll
                for (int r = 0; r < 4; ++r) rs[mi][r] += __shfl_xor(rs[mi][r], d);
#pragma unroll
            for (int r = 0; r < 4; ++r) lrow[mi][r] = lrow[mi][r] * ef[mi][r] + rs[mi][r];
#pragma unroll
            for (int df = 0; df < 4; ++df)
#pragma unroll
                for (int r = 0; r < 4; ++r) oacc[mi][df][r] *= ef[mi][r];
        }

        // O += P @ V
#pragma unroll
        for (int kf = 0; kf < 2; ++kf) {
            bf16x8 pa[2];
#pragma unroll
            for (int mi = 0; mi < 2; ++mi)
                pa[mi] = ldb8(&Pl[w][mi * 16 + l15][kf * 32 + lg * 8]);
#pragma unroll
            for (int df = 0; df < 4; ++df) {
                bf16x8 vb = ldb8(&Vt[df * 16 + l15][kf * 32 + lg * 8]);
#pragma unroll
                for (int mi = 0; mi < 2; ++mi)
                    oacc[mi][df] = MFMA16(pa[mi], vb, oacc[mi][df]);
            }
        }
    }

    // epilogue: O /= l, store bf16 to ao[b][i][h*64+d]
#pragma unroll
    for (int mi = 0; mi < 2; ++mi) {
        f32x4 inv;
#pragma unroll
        for (int r = 0; r < 4; ++r) inv[r] = 1.0f / lrow[mi][r];
#pragma unroll
        for (int df = 0; df < 4; ++df)
#pragma unroll
            for (int r = 0; r < 4; ++r) {
                int i = qt * 128 + w * 32 + mi * 16 + lg * 4 + r;
                int d = df * 16 + l15;
                ao[(bb + i) * 256 + h * 64 + d] = f2bf(oacc[mi][df][r] * inv[r]);
            }
    }
}

// ---------------- kernel 5: out GEMM + bias + residual, transposed fp32 store ----------------
__global__ __launch_bounds__(256) void k_gemm_out(const unsigned short* __restrict__ aoin,
                                                  const unsigned short* __restrict__ wT,
                                                  const float* __restrict__ bias,
                                                  const float* __restrict__ x,
                                                  float* __restrict__ out) {
    int bid = blockIdx.x;            // 128 mtiles * 2 ntiles
    int mt = bid >> 1, nt = bid & 1;
    int tid = threadIdx.x;
    int w = tid >> 6, l = tid & 63;
    int l15 = l & 15, lg = l >> 4;
    int wm = (w >> 1) * 64, wn = (w & 1) * 64;

    __shared__ __align__(16) unsigned short Al[128 * 40];
    __shared__ __align__(16) unsigned short Bl[128 * 40];

    f32x4 acc[4][4] = {};

    int sr = tid >> 1;
    int sc = (tid & 1) << 4;
    const unsigned short* Ag = aoin + (((size_t)(mt * 128 + sr)) << 8) + sc;
    const unsigned short* Bg = wT + (((size_t)(nt * 128 + sr)) << 8) + sc;

    for (int kt = 0; kt < 256; kt += 32) {
        __syncthreads();
        {
            u16x8 a0 = *reinterpret_cast<const u16x8*>(Ag + kt);
            u16x8 a1 = *reinterpret_cast<const u16x8*>(Ag + kt + 8);
            u16x8 b0 = *reinterpret_cast<const u16x8*>(Bg + kt);
            u16x8 b1 = *reinterpret_cast<const u16x8*>(Bg + kt + 8);
            *reinterpret_cast<u16x8*>(&Al[sr * 40 + sc]) = a0;
            *reinterpret_cast<u16x8*>(&Al[sr * 40 + sc + 8]) = a1;
            *reinterpret_cast<u16x8*>(&Bl[sr * 40 + sc]) = b0;
            *reinterpret_cast<u16x8*>(&Bl[sr * 40 + sc + 8]) = b1;
        }
        __syncthreads();
        bf16x8 af[4], bfr[4];
#pragma unroll
        for (int mi = 0; mi < 4; ++mi)
            af[mi] = ldb8(&Al[(wm + mi * 16 + l15) * 40 + lg * 8]);
#pragma unroll
        for (int ni = 0; ni < 4; ++ni)
            bfr[ni] = ldb8(&Bl[(wn + ni * 16 + l15) * 40 + lg * 8]);
#pragma unroll
        for (int mi = 0; mi < 4; ++mi)
#pragma unroll
            for (int ni = 0; ni < 4; ++ni)
                acc[mi][ni] = MFMA16(af[mi], bfr[ni], acc[mi][ni]);
    }

    // out[b][n][i] = acc + bias[n] + x[b][n][i]; lane holds 4 consecutive i at fixed n
#pragma unroll
    for (int ni = 0; ni < 4; ++ni) {
        int n = nt * 128 + wn + ni * 16 + l15;
        float bz = bias[n];
#pragma unroll
        for (int mi = 0; mi < 4; ++mi) {
            int mg = mt * 128 + wm + mi * 16 + lg * 4;
            int bI = mg >> 10, i = mg & 1023;
            size_t o = (((size_t)(bI * 256 + n)) << 10) + i;
            float4 xr = *reinterpret_cast<const float4*>(x + o);
            float4 res;
            res.x = acc[mi][ni][0] + bz + xr.x;
            res.y = acc[mi][ni][1] + bz + xr.y;
            res.z = acc[mi][ni][2] + bz + xr.z;
            res.w = acc[mi][ni][3] + bz + xr.w;
            *reinterpret_cast<float4*>(out + o) = res;
        }
    }
}

extern "C" void kernel_launch(void* const* d_in, const int* in_sizes, int n_in,
                              void* d_out, int out_size, void* d_ws, size_t ws_size,
                              hipStream_t stream) {
    const float* x      = (const float*)d_in[0];
    const float* w_proj = (const float*)d_in[1];
    const float* b_proj = (const float*)d_in[2];
    const float* w_out  = (const float*)d_in[3];
    const float* b_out  = (const float*)d_in[4];
    float* out = (float*)d_out;

    char* ws = (char*)d_ws;
    unsigned short* xT     = (unsigned short*)(ws);                 //  8,388,608 B
    unsigned short* wprojT = (unsigned short*)(ws + 8388608);       //    393,216 B
    unsigned short* woutT  = (unsigned short*)(ws + 8781824);       //    131,072 B
    unsigned short* qkv    = (unsigned short*)(ws + 8912896);       // 25,165,824 B
    unsigned short* ao     = (unsigned short*)(ws + 34078720);      //  8,388,608 B
    // total 42,467,328 B

    k_weights<<<256, 256, 0, stream>>>(w_proj, w_out, wprojT, woutT);
    k_transpose_x<<<1024, 256, 0, stream>>>(x, xT);
    k_gemm_qkv<<<768, 256, 0, stream>>>(xT, wprojT, b_proj, qkv);
    k_attn<<<512, 256, 0, stream>>>(qkv, ao);
    k_gemm_out<<<256, 256, 0, stream>>>(ao, woutT, b_out, x, out);
}